// Round 1
// baseline (143.863 us; speedup 1.0000x reference)
//
#include <hip/hip_runtime.h>

#define BATCH 4096
#define DICT  16384
#define KDIM  512
#define CAT   128
#define ND    16              // d-slices (split-K over dict)
#define DSLICE (DICT/ND)      // 1024
#define DCH   64              // d-chunk per iteration
#define BT    128             // b rows per block

typedef __attribute__((ext_vector_type(4))) float          f32x4;
typedef __attribute__((ext_vector_type(8))) short          short8;
typedef __attribute__((ext_vector_type(8))) unsigned short ushort8;

__device__ __forceinline__ unsigned short f2bf(float f) {
  unsigned int u = __float_as_uint(f);
  return (unsigned short)((u + 0x7fffu + ((u >> 16) & 1u)) >> 16);  // RNE
}

#define AS1 __attribute__((address_space(1)))
#define AS3 __attribute__((address_space(3)))
__device__ __forceinline__ void gl_lds16(const void* g, void* l) {
  // 16B per lane, LDS dest = wave-uniform base + lane*16 (linear); swizzle is
  // pre-applied on the GLOBAL source address (m173 pattern).
  __builtin_amdgcn_global_load_lds((AS1 void*)(g), (AS3 void*)(l), 16, 0, 0);
}

// ---------- prep: rows -> bf16 + sum of squares (x and keys) ----------
__global__ void prep_rows(const float* __restrict__ in,
                          unsigned short* __restrict__ ob,
                          float* __restrict__ sums) {
  const int lane = threadIdx.x & 63, wv = threadIdx.x >> 6;
  const int row = blockIdx.x * 4 + wv;
  const float* rp = in + ((size_t)row << 9);
  float4 a = *(const float4*)(rp + lane * 8);
  float4 b = *(const float4*)(rp + lane * 8 + 4);
  float s = a.x*a.x + a.y*a.y + a.z*a.z + a.w*a.w
          + b.x*b.x + b.y*b.y + b.z*b.z + b.w*b.w;
  ushort8 o;
  o[0]=f2bf(a.x); o[1]=f2bf(a.y); o[2]=f2bf(a.z); o[3]=f2bf(a.w);
  o[4]=f2bf(b.x); o[5]=f2bf(b.y); o[6]=f2bf(b.z); o[7]=f2bf(b.w);
  *(ushort8*)(ob + ((size_t)row << 9) + lane * 8) = o;
  #pragma unroll
  for (int m = 32; m; m >>= 1) s += __shfl_xor(s, m);
  if (lane == 0) sums[row] = s;
}

// ---------- prep: V (16384x128) -> Vt bf16 (128x16384) ----------
__global__ void prep_vt(const float* __restrict__ V,
                        unsigned short* __restrict__ Vt) {
  __shared__ float t[64][129];   // +1 pad: transpose-read 2-way (free)
  const int d0 = blockIdx.x * 64;
  const int tid = threadIdx.x;
  #pragma unroll
  for (int j = 0; j < 32; ++j) {
    int idx = j * 256 + tid;                 // 0..8191
    t[idx >> 7][idx & 127] = V[((size_t)d0 << 7) + idx];
  }
  __syncthreads();
  #pragma unroll
  for (int j = 0; j < 32; ++j) {
    int idx = j * 256 + tid;
    int cc = idx >> 6, dd = idx & 63;
    Vt[((size_t)cc << 14) + d0 + dd] = f2bf(t[dd][cc]);
  }
}

// ---------- fused: kern = 10000/(sq+1); KV_part[slice] += kern^T * V ----------
__global__ __launch_bounds__(256, 2)
void varkeys_fused(const unsigned short* __restrict__ xb,
                   const unsigned short* __restrict__ kb,
                   const unsigned short* __restrict__ vt,
                   const float* __restrict__ sx,
                   const float* __restrict__ sk,
                   float* __restrict__ kvp) {
  __shared__ __attribute__((aligned(16))) char lds[61440];
  char* As = lds;                 // keys chunk  [64 d][64 k]  8 KB (swizzled)
  char* Bs = lds + 8192;          // x chunk    [128 b][64 k] 16 KB (swizzled)
  char* Vs = lds + 24576;         // Vt chunk   [128 c][64 d] 16 KB (swizzled)
  char* Ps = lds + 40960;         // per-wave P [4][32 b][64 d] 16 KB (swizzled)
  float* sks = (float*)(lds + 57344);  // sk slice, 1024 f32

  const int tid  = threadIdx.x;
  const int lane = tid & 63;
  const int wv   = tid >> 6;
  const int c    = lane & 15;
  const int h    = lane >> 4;
  const int sw   = (lane & 7) << 4;   // row-XOR swizzle (row&7 == c&7 everywhere)

  const int bid    = blockIdx.x;
  const int btile  = bid & 31;
  const int dslice = bid >> 5;
  const int b0     = btile * BT;
  const int dbase  = dslice * DSLICE;

  { f32x4 v = *(const f32x4*)(sk + dbase + tid * 4);
    *(f32x4*)(sks + tid * 4) = v; }
  const float sxv0 = sx[b0 + wv * 32 + c];
  const float sxv1 = sx[b0 + wv * 32 + 16 + c];

  const f32x4 zero = {0.f, 0.f, 0.f, 0.f};
  f32x4 acc[2][8];
  #pragma unroll
  for (int i = 0; i < 2; ++i)
    #pragma unroll
    for (int j = 0; j < 8; ++j) acc[i][j] = zero;

  const char* xbB = (const char*)xb;
  const char* kbB = (const char*)kb;
  const char* vtB = (const char*)vt;

  for (int dc = 0; dc < DSLICE / DCH; ++dc) {
    const int dg = dbase + dc * DCH;

    f32x4 S[4][2];
    #pragma unroll
    for (int i = 0; i < 4; ++i) { S[i][0] = zero; S[i][1] = zero; }

    for (int kk = 0; kk < KDIM / 64; ++kk) {
      __syncthreads();                       // prev readers done before overwrite
      #pragma unroll
      for (int r = 0; r < 2; ++r) {          // keys 8KB
        int L = r * 4096 + wv * 1024 + lane * 16;
        int row = L >> 7, inb = L & 127;
        gl_lds16(kbB + (((size_t)(dg + row)) << 10) + (kk << 7) + (inb ^ ((row & 7) << 4)),
                 As + r * 4096 + wv * 1024);
      }
      #pragma unroll
      for (int r = 0; r < 4; ++r) {          // x 16KB
        int L = r * 4096 + wv * 1024 + lane * 16;
        int row = L >> 7, inb = L & 127;
        gl_lds16(xbB + (((size_t)(b0 + row)) << 10) + (kk << 7) + (inb ^ ((row & 7) << 4)),
                 Bs + r * 4096 + wv * 1024);
      }
      if (kk == 0) {                         // Vt 16KB, once per d-chunk
        #pragma unroll
        for (int r = 0; r < 4; ++r) {
          int L = r * 4096 + wv * 1024 + lane * 16;
          int row = L >> 7, inb = L & 127;
          gl_lds16(vtB + (((size_t)row) << 15) + ((size_t)dg << 1) + (inb ^ ((row & 7) << 4)),
                   Vs + r * 4096 + wv * 1024);
        }
      }
      __syncthreads();                       // staging complete (vmcnt drained)

      // GEMM1: S[d][b] += keys·x^T   (A rows=d, B cols=b)
      #pragma unroll
      for (int kf = 0; kf < 2; ++kf) {
        const int ko = (kf * 64 + h * 16) ^ sw;
        short8 bf0 = *(const short8*)(Bs + ((wv * 32 + c) << 7) + ko);
        short8 bf1 = *(const short8*)(Bs + ((wv * 32 + 16 + c) << 7) + ko);
        #pragma unroll
        for (int i = 0; i < 4; ++i) {
          short8 af = *(const short8*)(As + ((i * 16 + c) << 7) + ko);
          S[i][0] = __builtin_amdgcn_mfma_f32_16x16x32_bf16(af, bf0, S[i][0], 0, 0, 0);
          S[i][1] = __builtin_amdgcn_mfma_f32_16x16x32_bf16(af, bf1, S[i][1], 0, 0, 0);
        }
      }
    }

    // transform: kern = 10000/(sk + sx - 2*dot + 1), pack bf16 -> per-wave P
    #pragma unroll
    for (int i = 0; i < 4; ++i) {
      const f32x4 skv = *(const f32x4*)(sks + dc * 64 + i * 16 + h * 4);
      #pragma unroll
      for (int fj = 0; fj < 2; ++fj) {
        const float sxv = fj ? sxv1 : sxv0;
        f32x4 s = S[i][fj];
        float k0 = 10000.f * __builtin_amdgcn_rcpf(skv[0] + sxv - 2.f * s[0] + 1.f);
        float k1 = 10000.f * __builtin_amdgcn_rcpf(skv[1] + sxv - 2.f * s[1] + 1.f);
        float k2 = 10000.f * __builtin_amdgcn_rcpf(skv[2] + sxv - 2.f * s[2] + 1.f);
        float k3 = 10000.f * __builtin_amdgcn_rcpf(skv[3] + sxv - 2.f * s[3] + 1.f);
        unsigned int w0 = (unsigned int)f2bf(k0) | ((unsigned int)f2bf(k1) << 16);
        unsigned int w1 = (unsigned int)f2bf(k2) | ((unsigned int)f2bf(k3) << 16);
        int b = fj * 16 + c;
        char* p = Ps + (wv << 12) + (b << 7) + ((i * 32 + h * 8) ^ sw);
        ((unsigned int*)p)[0] = w0;
        ((unsigned int*)p)[1] = w1;
      }
    }

    // GEMM2: KV[b][c] += P[b][d] * Vt^T[d][c]  (same-wave P, no barrier)
    #pragma unroll
    for (int dk = 0; dk < 2; ++dk) {
      const int ko = (dk * 64 + h * 16) ^ sw;
      short8 pa0 = *(const short8*)(Ps + (wv << 12) + (c << 7) + ko);
      short8 pa1 = *(const short8*)(Ps + (wv << 12) + ((16 + c) << 7) + ko);
      #pragma unroll
      for (int fc = 0; fc < 8; ++fc) {
        short8 vb = *(const short8*)(Vs + ((fc * 16 + c) << 7) + ko);
        acc[0][fc] = __builtin_amdgcn_mfma_f32_16x16x32_bf16(pa0, vb, acc[0][fc], 0, 0, 0);
        acc[1][fc] = __builtin_amdgcn_mfma_f32_16x16x32_bf16(pa1, vb, acc[1][fc], 0, 0, 0);
      }
    }
  }

  // epilogue: write this slice's partial KV
  float* op = kvp + (((size_t)dslice * BATCH + b0 + wv * 32) << 7);
  #pragma unroll
  for (int fb = 0; fb < 2; ++fb)
    #pragma unroll
    for (int r = 0; r < 4; ++r) {
      int brow = fb * 16 + h * 4 + r;
      #pragma unroll
      for (int fc = 0; fc < 8; ++fc)
        op[((size_t)brow << 7) + fc * 16 + c] = acc[fb][fc][r];
    }
}

// ---------- reduce ND slices + row-normalize ----------
__global__ void reduce_norm(const float* __restrict__ part, float* __restrict__ out) {
  const int lane = threadIdx.x & 63, wv = threadIdx.x >> 6;
  const int b = blockIdx.x * 4 + wv;
  float v0 = 0.f, v1 = 0.f;
  #pragma unroll
  for (int s = 0; s < ND; ++s) {
    const float* p = part + ((((size_t)s << 12) + b) << 7);
    v0 += p[lane]; v1 += p[lane + 64];
  }
  float t = v0 + v1;
  #pragma unroll
  for (int m = 32; m; m >>= 1) t += __shfl_xor(t, m);
  out[((size_t)b << 7) + lane]      = v0 / t;
  out[((size_t)b << 7) + lane + 64] = v1 / t;
}

extern "C" void kernel_launch(void* const* d_in, const int* in_sizes, int n_in,
                              void* d_out, int out_size, void* d_ws, size_t ws_size,
                              hipStream_t stream) {
  (void)in_sizes; (void)n_in; (void)out_size; (void)ws_size;
  const float* x    = (const float*)d_in[0];
  const float* keys = (const float*)d_in[1];
  const float* V    = (const float*)d_in[2];
  float* out = (float*)d_out;
  char* ws = (char*)d_ws;
  // ws layout (needs 57 MiB): xb 4M | kb 16M | vt 4M | sx 16K | sk 64K | kv_part 32M
  unsigned short* xb = (unsigned short*)(ws);
  unsigned short* kb = (unsigned short*)(ws + ((size_t)4 << 20));
  unsigned short* vt = (unsigned short*)(ws + ((size_t)20 << 20));
  float* sx  = (float*)(ws + ((size_t)24 << 20));
  float* sk  = (float*)(ws + ((size_t)24 << 20) + (1 << 16));
  float* kvp = (float*)(ws + ((size_t)25 << 20));

  prep_rows<<<BATCH / 4, 256, 0, stream>>>(x, xb, sx);
  prep_rows<<<DICT / 4, 256, 0, stream>>>(keys, kb, sk);
  prep_vt<<<DICT / 64, 256, 0, stream>>>(V, vt);
  varkeys_fused<<<(BATCH / BT) * ND, 256, 0, stream>>>(xb, kb, vt, sx, sk, kvp);
  reduce_norm<<<BATCH / 4, 256, 0, stream>>>(kvp, out);
}